// Round 15
// baseline (811.007 us; speedup 1.0000x reference)
//
#include <hip/hip_runtime.h>

// ---------------------------------------------------------------------------
// DeformableAttnBlock — round 15: k_sample 4-way split (ch-half x tap-half,
// shfl combine, 2560 blocks); t_pad merged into k_wprep. 9 launches.
// B=2, T=5, C=192, H=W=64, NH=4, NL=5, NP=4, DH=48
// ---------------------------------------------------------------------------

#define HWPX 4096
#define PPXN 4624      // 68*68
#define LQ   20480

typedef __attribute__((ext_vector_type(8))) short  short8;
typedef __attribute__((ext_vector_type(4))) short  short4v;
typedef __attribute__((ext_vector_type(4))) float  f32x4;
typedef __attribute__((ext_vector_type(4))) float  float4v;

__device__ __forceinline__ unsigned short f2bf(float f) {
    unsigned u = __float_as_uint(f);
    unsigned r = (u + 0x7FFF + ((u >> 16) & 1)) >> 16;   // RNE
    return (unsigned short)r;
}
__device__ __forceinline__ float bf2f(unsigned short s) {
    return __uint_as_float(((unsigned)s) << 16);
}

__device__ __forceinline__ void gl_lds16(const unsigned short* g, unsigned short* l) {
    __builtin_amdgcn_global_load_lds(
        (const __attribute__((address_space(1))) unsigned int*)g,
        (__attribute__((address_space(3))) unsigned int*)l, 16, 0, 0);
}

// ---------------------------------------------------------------------------
__device__ __forceinline__ float bsample(const float* __restrict__ p, float sx, float sy) {
    sx = fminf(fmaxf(sx, 0.f), 63.f);
    sy = fminf(fmaxf(sy, 0.f), 63.f);
    float x0 = floorf(sx), y0 = floorf(sy);
    int ix0 = (int)x0, iy0 = (int)y0;
    int ix1 = ix0 < 63 ? ix0 + 1 : 63;
    int iy1 = iy0 < 63 ? iy0 + 1 : 63;
    float wx = sx - x0, wy = sy - y0;
    float v00 = p[iy0*64+ix0], v01 = p[iy0*64+ix1];
    float v10 = p[iy1*64+ix0], v11 = p[iy1*64+ix1];
    return (v00*(1.f-wx) + v01*wx)*(1.f-wy) + (v10*(1.f-wx) + v11*wx)*wy;
}

__device__ void dev_flow(int i, const float* __restrict__ ff,
                         const float* __restrict__ fb, float* __restrict__ flows) {
    int b = i >> 12, pix = i & 4095;
    int x = pix & 63, y = pix >> 6;
    const float* ff01 = ff + (size_t)(b*4+0)*2*HWPX;
    const float* ff12 = ff + (size_t)(b*4+1)*2*HWPX;
    const float* fb32 = fb + (size_t)(b*4+2)*2*HWPX;
    const float* fb43 = fb + (size_t)(b*4+3)*2*HWPX;
    float* F = flows + (size_t)b*5*2*HWPX;
    float ax = ff01[pix], ay = ff01[HWPX+pix];
    float sx = bsample(ff12,      (float)x+ax, (float)y+ay);
    float sy = bsample(ff12+HWPX, (float)x+ax, (float)y+ay);
    F[0*2*HWPX + pix]        = ax + sx;
    F[0*2*HWPX + HWPX + pix] = ay + sy;
    F[1*2*HWPX + pix]        = ff12[pix];
    F[1*2*HWPX + HWPX + pix] = ff12[HWPX+pix];
    F[2*2*HWPX + pix]        = 0.f;
    F[2*2*HWPX + HWPX + pix] = 0.f;
    F[3*2*HWPX + pix]        = fb32[pix];
    F[3*2*HWPX + HWPX + pix] = fb32[HWPX+pix];
    float bx = fb43[pix], by = fb43[HWPX+pix];
    float tx = bsample(fb32,      (float)x+bx, (float)y+by);
    float ty = bsample(fb32+HWPX, (float)x+bx, (float)y+by);
    F[4*2*HWPX + pix]        = bx + tx;
    F[4*2*HWPX + HWPX + pix] = by + ty;
}

__device__ void dev_wT(const float* __restrict__ w, unsigned short* __restrict__ wT,
                       int CI, int NKB, int cotile, int kblk, int tid) {
    unsigned short* dst = wT + ((size_t)(cotile*NKB + kblk))*18432;
    #pragma unroll
    for (int it = 0; it < 9; ++it) {
        int idx = it*256 + tid;
        int tap = idx >> 8, sub = idx & 255;
        int cg = sub >> 6, co = sub & 63;
        int cog = cotile*64 + co;
        int ci0 = kblk*32 + cg*8;
        short8 v;
        #pragma unroll
        for (int j = 0; j < 8; ++j) {
            int ci = ci0 + j;
            v[j] = (ci < CI) ? (short)f2bf(w[((size_t)cog*CI + ci)*9 + tap]) : (short)0;
        }
        *(short8*)(dst + (size_t)idx*8) = v;
    }
}

__device__ void dev_wg(const float* __restrict__ w1, const float* __restrict__ w2,
                       unsigned short* __restrict__ wg, int co_split, int CO,
                       int cotile, int tid) {
    unsigned short* dst = wg + (size_t)cotile*12288;
    #pragma unroll
    for (int it = 0; it < 6; ++it) {
        int idx = it*256 + tid;
        int kblk = idx >> 8, sub = idx & 255;
        int cg = sub >> 6, co = sub & 63;
        int cog = cotile*64 + co;
        int ci0 = kblk*32 + cg*8;
        short8 v = {};
        if (cog < CO) {
            const float* row = (cog < co_split) ? w1 + (size_t)cog*192
                                                : w2 + (size_t)(cog - co_split)*192;
            #pragma unroll
            for (int j = 0; j < 8; ++j) v[j] = (short)f2bf(row[ci0 + j]);
        }
        *(short8*)(dst + (size_t)idx*8) = v;
    }
}

__device__ void dev_pad(const float* __restrict__ in, unsigned short* __restrict__ outb,
                        int CI, int PITCH, int COFF, int img, int ppx_t, int cq, int tid) {
    int ppx = ppx_t*64 + (tid & 63);
    if (ppx >= PPXN) return;
    int c8 = (cq*4 + (tid >> 6))*8;
    unsigned short* dst = outb + ((size_t)img*PPXN + ppx)*PITCH;
    int py = ppx/68, pxc = ppx - py*68;
    if (py < 2 || py >= 66 || pxc < 2 || pxc >= 66) {
        short8 z = {};
        *(short8*)(dst + c8) = z;
        if (COFF) *(short8*)(dst + COFF + c8) = z;
        return;
    }
    int pix = ((py-2)<<6) + (pxc-2);
    short8 o;
    #pragma unroll
    for (int j = 0; j < 8; ++j)
        o[j] = (short)f2bf(in[((size_t)img*CI + c8 + j)*HWPX + pix]);
    *(short8*)(dst + COFF + c8) = o;
}

// ---------------------------------------------------------------------------
// k_wprep: flow + all weight transforms + srcframe->out2 copy + frame pad.
// [0,32) flow | [32,497) wT_qk | [497,947) wT_v | [947,965) wT_ff |
// [965,1001) wT_f1 | [1001,1019) wT_f2 | [1019,1029) wg x3 |
// [1029,1989) copy | [1989,6369) pad frame->P_v
__global__ __launch_bounds__(256) void k_wprep(
    const float* __restrict__ flow_f, const float* __restrict__ flow_b,
    float* __restrict__ flows,
    const float* __restrict__ w_qk, unsigned short* __restrict__ wT_qk,
    const float* __restrict__ w_v,  unsigned short* __restrict__ wT_v,
    const float* __restrict__ w_ff, unsigned short* __restrict__ wT_ff,
    const float* __restrict__ w_f1, unsigned short* __restrict__ wT_f1,
    const float* __restrict__ w_f2, unsigned short* __restrict__ wT_f2,
    const float* __restrict__ w_vp, const float* __restrict__ w_off,
    const float* __restrict__ w_at, const float* __restrict__ w_out,
    unsigned short* __restrict__ wg_vp, unsigned short* __restrict__ wg_oa,
    unsigned short* __restrict__ wg_out,
    const float* __restrict__ srcframe, float* __restrict__ out2,
    const float* __restrict__ frame, unsigned short* __restrict__ P_v)
{
    int bid = blockIdx.x, tid = threadIdx.x;
    if (bid < 32) {
        dev_flow(bid*256 + tid, flow_f, flow_b, flows);
    } else if (bid < 497) {
        int p = bid - 32;   dev_wT(w_qk, wT_qk, 976, 31, p/31, p%31, tid);
    } else if (bid < 947) {
        int p = bid - 497;  dev_wT(w_v,  wT_v,  960, 30, p/30, p%30, tid);
    } else if (bid < 965) {
        int p = bid - 947;  dev_wT(w_ff, wT_ff, 192, 6,  p/6,  p%6,  tid);
    } else if (bid < 1001) {
        int p = bid - 965;  dev_wT(w_f1, wT_f1, 384, 12, p/12, p%12, tid);
    } else if (bid < 1019) {
        int p = bid - 1001; dev_wT(w_f2, wT_f2, 192, 6,  p/6,  p%6,  tid);
    } else if (bid < 1029) {
        int g = bid - 1019;
        if (g < 3)      dev_wg(w_vp,  nullptr, wg_vp, 192, 192, g,   tid);
        else if (g < 7) dev_wg(w_off, w_at,    wg_oa, 160, 240, g-3, tid);
        else            dev_wg(w_out, nullptr, wg_out, 192, 192, g-7, tid);
    } else if (bid < 1989) {
        // srcframe -> out2: 7,864,320 floats = 1,966,080 float4; 8 per thread
        int c = bid - 1029;
        const float4v* s4 = (const float4v*)srcframe;
        float4v* d4 = (float4v*)out2;
        #pragma unroll
        for (int it = 0; it < 8; ++it) {
            int idx = it*245760 + c*256 + tid;
            d4[idx] = s4[idx];
        }
    } else {
        // frame -> P_v padded tok bf16: 4380 = 2 imgs x 30 cq x 73 ppx_t
        int p = bid - 1989;
        int img = p / 2190, rem = p - img*2190;
        int ppx_t = rem % 73, cq = rem / 73;
        dev_pad(frame, P_v, 960, 960, 0, img, ppx_t, cq, tid);
    }
}

// ---------------------------------------------------------------------------
// K2: fused qk_in assembly from bf16 token-major padded P_v.
__global__ void k_qkin(const unsigned short* __restrict__ Pv,
                       const float* __restrict__ ff, const float* __restrict__ fb,
                       const float* __restrict__ flows,
                       unsigned short* __restrict__ Pqk)
{
    int ppx = blockIdx.x*64 + threadIdx.x;
    if (ppx >= PPXN) return;
    int b = blockIdx.z;
    int c8 = (blockIdx.y*4 + threadIdx.y)*8;
    unsigned short* dst = Pqk + ((size_t)b*PPXN + ppx)*992 + c8;
    int py = ppx/68, pxc = ppx - py*68;
    short8 o = {};
    if (py >= 2 && py < 66 && pxc >= 2 && pxc < 66 && c8 < 976) {
        int y = py-2, x = pxc-2, pix = (y<<6)+x;
        if (c8 >= 960) {
            #pragma unroll
            for (int j = 0; j < 8; ++j) {
                int k = c8 - 960 + j;
                float v = (k < 8) ? ff[((size_t)b*8 + k)*HWPX + pix]
                                  : fb[((size_t)b*8 + k - 8)*HWPX + pix];
                o[j] = (short)f2bf(v);
            }
        } else {
            const unsigned short* Pvb = Pv + (size_t)b*PPXN*960;
            int slot = c8/192;
            if (slot == 2) {
                o = *(const short8*)(Pvb + (size_t)ppx*960 + c8);
            } else {
                const float* F = flows + ((size_t)(b*5 + slot)*2)*HWPX;
                float sx = fminf(fmaxf((float)x + F[pix], 0.f), 63.f);
                float sy = fminf(fmaxf((float)y + F[HWPX + pix], 0.f), 63.f);
                float x0 = floorf(sx), y0 = floorf(sy);
                int ix0 = (int)x0, iy0 = (int)y0;
                int ix1 = ix0 < 63 ? ix0+1 : 63, iy1 = iy0 < 63 ? iy0+1 : 63;
                float wx = sx - x0, wy = sy - y0;
                float w00 = (1.f-wx)*(1.f-wy), w01 = wx*(1.f-wy);
                float w10 = (1.f-wx)*wy,       w11 = wx*wy;
                short8 v00 = *(const short8*)(Pvb + ((size_t)((iy0+2)*68 + ix0+2))*960 + c8);
                short8 v01 = *(const short8*)(Pvb + ((size_t)((iy0+2)*68 + ix1+2))*960 + c8);
                short8 v10 = *(const short8*)(Pvb + ((size_t)((iy1+2)*68 + ix0+2))*960 + c8);
                short8 v11 = *(const short8*)(Pvb + ((size_t)((iy1+2)*68 + ix1+2))*960 + c8);
                #pragma unroll
                for (int j = 0; j < 8; ++j) {
                    float v = bf2f((unsigned short)v00[j])*w00 + bf2f((unsigned short)v01[j])*w01
                            + bf2f((unsigned short)v10[j])*w10 + bf2f((unsigned short)v11[j])*w11;
                    o[j] = (short)f2bf(v);
                }
            }
        }
    }
    *(short8*)dst = o;
}

// ---------------------------------------------------------------------------
// k_conv: MFMA implicit-GEMM 3x3 conv (round-9/12 exact, verified 272-277us).
template<int ROWS, int DIL, int OUTK, bool LEAKY, int RESK>
__global__ __launch_bounds__(256, 2) void k_conv(
    const unsigned short* __restrict__ P0, const unsigned short* __restrict__ P1,
    int CIP0, int CIP1, int NKB0, int NKB1,
    const unsigned short* __restrict__ wT0, const unsigned short* __restrict__ wT1,
    const float* __restrict__ bias0, const float* __restrict__ bias1,
    const float* __restrict__ resF, const unsigned short* __restrict__ resB, int resPitch,
    float* __restrict__ outF,
    unsigned short* __restrict__ outB0, unsigned short* __restrict__ outB1,
    int outPitch, int outCoff, int njobs)
{
    constexpr int RR     = ROWS*4 + 2*DIL;
    constexpr int XP     = 64 + 2*DIL;
    constexpr int PLANE  = RR*XP*16;
    constexpr int NCH    = RR*XP*4;
    constexpr int NXS    = (NCH + 255)/256;
    constexpr int TILEPX = ROWS*4*64;
    constexpr int SMEM_K = 4*PLANE + 36864;
    constexpr int SMEM_E = (OUTK <= 1) ? TILEPX*72*2 : 0;
    constexpr int SMEMSZ = SMEM_K > SMEM_E ? SMEM_K : SMEM_E;
    __shared__ __align__(16) unsigned char smem[SMEMSZ];
    unsigned char*  s_x = smem;
    unsigned short* s_w = (unsigned short*)(smem + 4*PLANE);

    int tid = threadIdx.x & 255;
    int gx = gridDim.x, gy = gridDim.y, gz = gridDim.z;
    int lin = blockIdx.x + gx*(blockIdx.y + gy*blockIdx.z);
    int tot = gx*gy*gz;
    if ((tot & 7) == 0) { int q = tot >> 3; lin = (lin & 7)*q + (lin >> 3); }
    int cotile = lin % gx; int rem = lin / gx;
    int ytile = rem % gy;  int z = rem / gy;

    int sel = (njobs == 2) ? (z >> 1) : 0;
    int img = (njobs == 2) ? (z & 1)  : z;
    const unsigned short* P  = sel ? P1  : P0;
    const unsigned short* wT = sel ? wT1 : wT0;
    const float* bias        = sel ? bias1 : bias0;
    unsigned short* outB     = sel ? outB1 : outB0;
    int CIP = sel ? CIP1 : CIP0;
    int NKB = sel ? NKB1 : NKB0;

    int y0 = ytile * (ROWS*4);
    const unsigned short* Pi = P + (size_t)img*PPXN*CIP;
    int w = tid >> 6, lane = tid & 63, lm = lane & 15, cig = lane >> 4;

    auto stage_x = [&](int kb) {
        int k0 = kb*32;
        #pragma unroll
        for (int it = 0; it < NXS; ++it) {
            int li = it*256 + tid;
            if (li < NCH) {
                int p = li / (RR*XP), rm = li - p*(RR*XP);
                int r = rm / XP, c = rm - r*XP;
                gl_lds16(Pi + ((size_t)((y0 + 2 - DIL + r)*68 + c + 2 - DIL))*CIP + k0 + p*8,
                         (unsigned short*)(s_x + li*16));
            }
        }
    };
    auto stage_w = [&](int kb) {
        const unsigned short* ws = wT + ((size_t)(cotile*NKB + kb))*18432;
        #pragma unroll
        for (int it = 0; it < 9; ++it)
            gl_lds16(ws + (size_t)(it*256+tid)*8, &s_w[(it*256+tid)*8]);
    };

    stage_x(0); stage_w(0);
    __syncthreads();

    f32x4 acc[4][ROWS*4] = {};
    for (int kb = 0; kb < NKB; ++kb) {
        __builtin_amdgcn_s_setprio(1);
        #pragma unroll
        for (int t = 0; t < 9; ++t) {
            int ky = t/3, kx = t - ky*3;
            short8 A[4];
            #pragma unroll
            for (int mb = 0; mb < 4; ++mb)
                A[mb] = *(const short8*)&s_w[((t*4 + cig)*64 + mb*16 + lm)*8];
            #pragma unroll
            for (int s = 0; s < ROWS; ++s) {
                short8 Bf[4];
                #pragma unroll
                for (int nc = 0; nc < 4; ++nc)
                    Bf[nc] = *(const short8*)&s_x[cig*PLANE +
                               ((w*ROWS + s + ky*DIL)*XP + nc*16 + lm + kx*DIL)*16];
                #pragma unroll
                for (int mb = 0; mb < 4; ++mb)
                    #pragma unroll
                    for (int nc = 0; nc < 4; ++nc)
                        acc[mb][s*4+nc] = __builtin_amdgcn_mfma_f32_16x16x32_bf16(
                            A[mb], Bf[nc], acc[mb][s*4+nc], 0, 0, 0);
            }
        }
        __builtin_amdgcn_s_setprio(0);
        __syncthreads();
        if (kb + 1 < NKB) { stage_x(kb+1); stage_w(kb+1); }
        __syncthreads();
    }

    if (OUTK == 0 || OUTK == 1) {
        unsigned short* epi = (unsigned short*)smem;
        #pragma unroll
        for (int mb = 0; mb < 4; ++mb) {
            int cob = cotile*64 + mb*16 + cig*4;
            int col = mb*16 + cig*4;
            #pragma unroll
            for (int s = 0; s < ROWS; ++s) {
                int lr = w*ROWS + s;
                #pragma unroll
                for (int nc = 0; nc < 4; ++nc) {
                    int x = nc*16 + lm;
                    int px_l = lr*64 + x;
                    int gpx = y0*64 + px_l;
                    short4v sv;
                    #pragma unroll
                    for (int r = 0; r < 4; ++r) {
                        float v = acc[mb][s*4+nc][r] + bias[cob + r];
                        if (LEAKY) v = v >= 0.f ? v : 0.1f*v;
                        if (RESK == 1) v += resF[((size_t)img*192 + cob + r)*HWPX + gpx];
                        sv[r] = (short)f2bf(v);
                    }
                    *(short4v*)&epi[px_l*72 + col] = sv;
                }
            }
        }
        __syncthreads();
        constexpr int NCPY = TILEPX/32;
        int slot = (OUTK == 0) ? (cotile*64)/192 : 0;
        int ccb  = (OUTK == 0) ? (cotile*64)%192 : (cotile*64 + outCoff);
        #pragma unroll
        for (int it2 = 0; it2 < NCPY; ++it2) {
            int li = it2*256 + tid;
            int px_l = li >> 3, sub = li & 7;
            short8 v = *(const short8*)&epi[px_l*72 + sub*8];
            int gpx = y0*64 + px_l;
            if (OUTK == 0) {
                *(short8*)(outB + ((size_t)(img*5 + slot)*HWPX + gpx)*192 + ccb + sub*8) = v;
            } else {
                int ppx = ((gpx>>6)+2)*68 + (gpx&63) + 2;
                *(short8*)(outB0 + ((size_t)img*PPXN + ppx)*outPitch + ccb + sub*8) = v;
            }
        }
    } else {
        #pragma unroll
        for (int mb = 0; mb < 4; ++mb) {
            int cob = cotile*64 + mb*16 + cig*4;
            #pragma unroll
            for (int s = 0; s < ROWS; ++s) {
                int y = y0 + w*ROWS + s;
                #pragma unroll
                for (int nc = 0; nc < 4; ++nc) {
                    int x = nc*16 + lm;
                    int px = (y<<6) + x;
                    int ppx = (y+2)*68 + x + 2;
                    short4v rv;
                    if (RESK == 2)
                        rv = *(const short4v*)(resB + ((size_t)img*PPXN + ppx)*resPitch + cob);
                    #pragma unroll
                    for (int r = 0; r < 4; ++r) {
                        float v = acc[mb][s*4+nc][r] + bias[cob + r];
                        if (LEAKY) v = v >= 0.f ? v : 0.1f*v;
                        if (RESK == 1) v += resF[((size_t)img*192 + cob + r)*HWPX + px];
                        if (RESK == 2) v += bf2f((unsigned short)rv[r]);
                        outF[((size_t)img*192 + cob + r)*HWPX + px] = v;
                    }
                }
            }
        }
    }
}

// ---------------------------------------------------------------------------
// GEMM inner core (K=192, 64co x 256px tile); shared arrays declared by caller.
#define GEMM_CORE(Xi, WG_, cotile_)                                              \
    _Pragma("unroll")                                                            \
    for (int it = 0; it < 6; ++it)                                               \
        gl_lds16(WG_ + (size_t)(cotile_)*12288 + (it*256+tid)*8,                 \
                 &s_w[(it*256+tid)*8]);                                          \
    short8 xr[4];                                                                \
    _Pragma("unroll")                                                            \
    for (int it = 0; it < 4; ++it)                                               \
        xr[it] = *(const short8*)(Xi + (size_t)(px0 + tid)*192 + it*8);          \
    _Pragma("unroll")                                                            \
    for (int it = 0; it < 4; ++it)                                               \
        *(short8*)&s_x[0][it*4096 + tid*16] = xr[it];                            \
    __syncthreads();                                                             \
    int w = tid >> 6, lane = tid & 63, lm = lane & 15, cig = lane >> 4;          \
    f32x4 acc[4][4] = {};                                                        \
    int xb = 0;                                                                  \
    for (int kb = 0; kb < 6; ++kb) {                                             \
        bool pf = (kb < 5);                                                      \
        if (pf) {                                                                \
            int k0 = (kb+1)*32;                                                  \
            _Pragma("unroll")                                                    \
            for (int it = 0; it < 4; ++it)                                       \
                xr[it] = *(const short8*)(Xi + (size_t)(px0 + tid)*192 + k0 + it*8); \
        }                                                                        \
        short8 A[4], Bf[4];                                                      \
        _Pragma("unroll")                                                        \
        for (int nb = 0; nb < 4; ++nb)                                           \
            Bf[nb] = *(const short8*)&s_x[xb][cig*4096 + (w*64 + nb*16 + lm)*16];\
        _Pragma("unroll")                                                        \
        for (int mb = 0; mb < 4; ++mb)                                           \
            A[mb] = *(const short8*)&s_w[((kb*4 + cig)*64 + mb*16 + lm)*8];      \
        _Pragma("unroll")                                                        \
        for (int mb = 0; mb < 4; ++mb)                                           \
            _Pragma("unroll")                                                    \
            for (int nb = 0; nb < 4; ++nb)                                       \
                acc[mb][nb] = __builtin_amdgcn_mfma_f32_16x16x32_bf16(           \
                    A[mb], Bf[nb], acc[mb][nb], 0, 0, 0);                        \
        if (pf) {                                                                \
            _Pragma("unroll")                                                    \
            for (int it = 0; it < 4; ++it)                                       \
                *(short8*)&s_x[xb^1][it*4096 + tid*16] = xr[it];                 \
        }                                                                        \
        __syncthreads();                                                         \
        xb ^= 1;                                                                 \
    }

// k_gemmA (flat 2110): [0,480) vproj -> vp h-major [img][4][4096][48];
// [480,1120) off/attn -> offs/aw fp32; [1120,2110) border zeroes P_ff & P_mid.
__global__ __launch_bounds__(256) void k_gemmA(
    const unsigned short* __restrict__ Xv, const unsigned short* __restrict__ WGv,
    const float* __restrict__ bvp, unsigned short* __restrict__ vp,
    const unsigned short* __restrict__ Xq, const unsigned short* __restrict__ WGq,
    const float* __restrict__ boff, const float* __restrict__ batt,
    float* __restrict__ offs, float* __restrict__ aw,
    unsigned short* __restrict__ P_ff, unsigned short* __restrict__ P_mid)
{
    __shared__ unsigned char  s_x[2][4*4096];
    __shared__ unsigned short s_w[12288];
    int tid = threadIdx.x & 255;
    int id = blockIdx.x;
    if (id < 480) {
        int cotile = id % 3, pxt = (id/3) % 16, img = id/48;
        int px0 = pxt*256;
        const unsigned short* Xi = Xv + (size_t)img*HWPX*192;
        GEMM_CORE(Xi, WGv, cotile)
        #pragma unroll
        for (int mb = 0; mb < 4; ++mb) {
            int cob = cotile*64 + mb*16 + cig*4;
            int h = cob/48, d = cob - h*48;
            #pragma unroll
            for (int nb = 0; nb < 4; ++nb) {
                int px = px0 + w*64 + nb*16 + lm;
                short4v s;
                #pragma unroll
                for (int r = 0; r < 4; ++r)
                    s[r] = (short)f2bf(acc[mb][nb][r] + bvp[cob + r]);
                *(short4v*)(vp + (((size_t)img*4 + h)*HWPX + px)*48 + d) = s;
            }
        }
    } else if (id < 1120) {
        int i2 = id - 480;
        int cotile = i2 % 4, pxt = (i2/4) % 16, img = i2/64;
        int px0 = pxt*256;
        const unsigned short* Xi = Xq + (size_t)img*HWPX*192;
        GEMM_CORE(Xi, WGq, cotile)
        int b = img/5, t = img - b*5;
        #pragma unroll
        for (int mb = 0; mb < 4; ++mb) {
            int cob = cotile*64 + mb*16 + cig*4;
            if (cob >= 240) continue;
            #pragma unroll
            for (int nb = 0; nb < 4; ++nb) {
                int px = px0 + w*64 + nb*16 + lm;
                #pragma unroll
                for (int r = 0; r < 4; ++r) {
                    int co = cob + r;
                    float bv = (co < 160) ? boff[co] : batt[co-160];
                    float v = acc[mb][nb][r] + bv;
                    if (co < 160) offs[((size_t)b*160 + co)*LQ + t*HWPX + px] = v;
                    else          aw[((size_t)b*80 + co-160)*LQ + t*HWPX + px] = v;
                }
            }
        }
    } else {
        int u = (id - 1120)*256 + tid;
        int c8i = u % 24; int r1 = u / 24;
        int b = r1 % 528; int r2 = r1 / 528;
        int img = r2 % 10; int buf = r2 / 10;
        int ppx;
        if (b < 136) ppx = b;
        else if (b < 272) ppx = 4488 + (b - 136);
        else { int b2 = b - 272; int row = 2 + (b2 >> 2); int cs = b2 & 3;
               ppx = row*68 + ((cs < 2) ? cs : cs + 64); }
        unsigned short* bp2 = buf ? P_mid : P_ff;
        short8 z = {};
        *(short8*)(bp2 + ((size_t)img*PPXN + ppx)*192 + c8i*8) = z;
    }
}

// k_tailB (flat 4860): [0,480) outproj GEMM -> P_ff interior;
// [480,4860) srcframe pad -> P_ffn1 cols 192..383 + borders.
__global__ __launch_bounds__(256) void k_tailB(
    const unsigned short* __restrict__ X, const unsigned short* __restrict__ WG,
    const float* __restrict__ b1, unsigned short* __restrict__ P_ff,
    const float* __restrict__ srcframe, unsigned short* __restrict__ P_ffn1)
{
    __shared__ unsigned char  s_x[2][4*4096];
    __shared__ unsigned short s_w[12288];
    int tid = threadIdx.x & 255;
    int id = blockIdx.x;
    if (id < 480) {
        int cotile = id % 3, pxt = (id/3) % 16, img = id/48;
        int px0 = pxt*256;
        const unsigned short* Xi = X + (size_t)img*HWPX*192;
        GEMM_CORE(Xi, WG, cotile)
        #pragma unroll
        for (int mb = 0; mb < 4; ++mb) {
            int cob = cotile*64 + mb*16 + cig*4;
            #pragma unroll
            for (int nb = 0; nb < 4; ++nb) {
                int px = px0 + w*64 + nb*16 + lm;
                int ppx = ((px>>6)+2)*68 + (px&63) + 2;
                short4v s;
                #pragma unroll
                for (int r = 0; r < 4; ++r)
                    s[r] = (short)f2bf(acc[mb][nb][r] + b1[cob + r]);
                *(short4v*)(P_ff + ((size_t)img*PPXN + ppx)*192 + cob) = s;
            }
        }
    } else {
        int p = id - 480;
        int img = p / 438, rem = p - img*438;
        int ppx_t = rem % 73, cq = rem / 73;
        dev_pad(srcframe, P_ffn1, 192, 384, 192, img, ppx_t, cq, tid);
    }
}

// ---------------------------------------------------------------------------
// K8: deformable sampling, fused softmax, 4-way split per (lq,h):
// qc = channel-half (24 ch), qt = tap-half (10 taps); combine via shfl_xor(2).
// vp h-major [img][4][4096][48].
__device__ __forceinline__ void addtap24(float* acc, const unsigned short* __restrict__ src, float w) {
    const short8* s8 = (const short8*)src;
    #pragma unroll
    for (int u = 0; u < 3; ++u) {
        short8 v = s8[u];
        #pragma unroll
        for (int j = 0; j < 8; ++j)
            acc[u*8+j] += w * bf2f((unsigned short)v[j]);
    }
}

__global__ __launch_bounds__(256) void k_sample(
    const unsigned short* __restrict__ vp, const float* __restrict__ offs,
    const float* __restrict__ aw, const float* __restrict__ flows,
    unsigned short* __restrict__ accout)
{
    int blk = blockIdx.x;                 // 2560 = 2 b x 1280 sub
    int b = blk / 1280, sub = blk - b*1280;
    int tid = threadIdx.x;
    int lq = sub*16 + (tid >> 4);         // 16 lq per block
    int h  = (tid >> 2) & 3;              // 4 heads
    int qt = (tid >> 1) & 1;              // tap half
    int qc = tid & 1;                     // channel half
    int pix = lq & 4095;
    int x = pix & 63, y = pix >> 6;
    const float* offp = offs + ((size_t)b*160 + h*40)*LQ + lq;
    const float* awp  = aw   + ((size_t)b*80  + h*20)*LQ + lq;
    float e[20];
    float m = -1e30f;
    #pragma unroll
    for (int j = 0; j < 20; ++j) { e[j] = awp[(size_t)j*LQ]; m = fmaxf(m, e[j]); }
    float ssum = 0.f;
    #pragma unroll
    for (int j = 0; j < 20; ++j) { e[j] = __expf(e[j]-m); ssum += e[j]; }
    float inv = 1.f/ssum;

    float acc[24];
    #pragma unroll
    for (int d = 0; d < 24; ++d) acc[d] = 0.f;

    int o0 = qt*10;
    #pragma unroll
    for (int oi = 0; oi < 10; ++oi) {
        int o = o0 + oi;
        int l = o >> 2, p = o & 3;
        (void)p;
        float fx = flows[((size_t)(b*5+l)*2+0)*HWPX + pix];
        float fy = flows[((size_t)(b*5+l)*2+1)*HWPX + pix];
        const unsigned short* vpl = vp + (((size_t)(b*5+l)*4 + h)*HWPX)*48 + qc*24;
        float ox = offp[(size_t)(2*o)*LQ];
        float oy = offp[(size_t)(2*o+1)*LQ];
        float wv = e[o]*inv;
        float sx = (float)x + ox + fx;
        float sy = (float)y + oy + fy;
        float x0f = floorf(sx), y0f = floorf(sy);
        float wx = sx - x0f, wy = sy - y0f;
        int ix0 = (int)x0f, iy0 = (int)y0f;
        float w00 = wv*(1.f-wx)*(1.f-wy), w01 = wv*wx*(1.f-wy);
        float w10 = wv*(1.f-wx)*wy,       w11 = wv*wx*wy;
        bool vx0 = (ix0 >= 0)  && (ix0 <= 63);
        bool vx1 = (ix0 >= -1) && (ix0 <= 62);
        bool vy0 = (iy0 >= 0)  && (iy0 <= 63);
        bool vy1 = (iy0 >= -1) && (iy0 <= 62);
        if (vy0 && vx0) addtap24(acc, vpl + (size_t)(iy0*64 + ix0)*48,       w00);
        if (vy0 && vx1) addtap24(acc, vpl + (size_t)(iy0*64 + ix0 + 1)*48,   w01);
        if (vy1 && vx0) addtap24(acc, vpl + (size_t)((iy0+1)*64 + ix0)*48,   w10);
        if (vy1 && vx1) addtap24(acc, vpl + (size_t)((iy0+1)*64 + ix0+1)*48, w11);
    }
    // combine tap halves (lanes tid and tid^2 are in the same wave)
    #pragma unroll
    for (int d = 0; d < 24; ++d)
        acc[d] += __shfl_xor(acc[d], 2);
    if (qt == 0) {
        unsigned short* dst = accout + ((size_t)b*LQ + lq)*192 + h*48 + qc*24;
        #pragma unroll
        for (int u = 0; u < 3; ++u) {
            short8 s;
            #pragma unroll
            for (int j = 0; j < 8; ++j) s[j] = (short)f2bf(acc[u*8+j]);
            *(short8*)(dst + u*8) = s;
        }
    }
}

// ---------------------------------------------------------------------------

extern "C" void kernel_launch(void* const* d_in, const int* in_sizes, int n_in,
                              void* d_out, int out_size, void* d_ws, size_t ws_size,
                              hipStream_t stream) {
    (void)in_sizes; (void)n_in; (void)out_size; (void)ws_size;
    const float* frame    = (const float*)d_in[0];
    const float* srcframe = (const float*)d_in[1];
    const float* flow_f   = (const float*)d_in[2];
    const float* flow_b   = (const float*)d_in[3];
    const float* w_qk  = (const float*)d_in[4];  const float* b_qk  = (const float*)d_in[5];
    const float* w_v   = (const float*)d_in[6];  const float* b_v   = (const float*)d_in[7];
    const float* w_vp  = (const float*)d_in[8];  const float* b_vp  = (const float*)d_in[9];
    const float* w_off = (const float*)d_in[10]; const float* b_off = (const float*)d_in[11];
    const float* w_at  = (const float*)d_in[12]; const float* b_at  = (const float*)d_in[13];
    const float* w_out = (const float*)d_in[14]; const float* b_out = (const float*)d_in[15];
    const float* w_ff  = (const float*)d_in[16]; const float* b_ff  = (const float*)d_in[17];
    const float* w_f1  = (const float*)d_in[18]; const float* b_f1  = (const float*)d_in[19];
    const float* w_f2  = (const float*)d_in[20]; const float* b_f2  = (const float*)d_in[21];
    float* out = (float*)d_out;
    char* W = (char*)d_ws;

    // ---- workspace layout (bytes), all regions disjoint; max 163,624,960 ----
    float*          flows  = (float*)(W + 0);                    // 327,680
    unsigned short* wT_qk  = (unsigned short*)(W + 327680);      // 17,141,760
    unsigned short* wT_v   = (unsigned short*)(W + 17469440);    // 16,588,800 -> 34,058,240
    unsigned short* P_qk   = (unsigned short*)(W + 34058240);    // 18,348,032
    unsigned short* P_ff   = P_qk;                               // reuse
    unsigned short* P_v    = (unsigned short*)(W + 52406272);    // 17,756,160
    unsigned short* P_mid  = P_v;                                // reuse
    unsigned short* Q_tok  = (unsigned short*)(W + 70162432);    // 15,728,640
    unsigned short* acc_tok= Q_tok;                              // reuse
    unsigned short* V_tok  = (unsigned short*)(W + 85891072);    // 15,728,640
    unsigned short* P_ffn1 = V_tok;                              // reuse (extends into vp after vp dead)
    unsigned short* vp     = (unsigned short*)(W + 101619712);   // 15,728,640
    float*          offs   = (float*)(W + 121403392);            // 26,214,400
    float*          aw     = (float*)(W + 147617792);            // 13,107,200 -> 160,724,992
    unsigned short* wT_ff  = (unsigned short*)(W + 160724992);   //   663,552
    unsigned short* wT_f1  = (unsigned short*)(W + 161388544);   // 1,327,104
    unsigned short* wT_f2  = (unsigned short*)(W + 162715648);   //   663,552
    unsigned short* wg_vp  = (unsigned short*)(W + 163379200);   //    73,728
    unsigned short* wg_oa  = (unsigned short*)(W + 163452928);   //    98,304
    unsigned short* wg_out = (unsigned short*)(W + 163551232);   //    73,728 -> 163,624,960

    dim3 bp(64, 4);

    // 1. flow + weight transforms + srcframe copy + frame pad (one dispatch)
    k_wprep<<<6369, 256, 0, stream>>>(
        flow_f, flow_b, flows,
        w_qk, wT_qk, w_v, wT_v, w_ff, wT_ff, w_f1, wT_f1, w_f2, wT_f2,
        w_vp, w_off, w_at, w_out, wg_vp, wg_oa, wg_out,
        srcframe, out + (size_t)2*5*192*HWPX, frame, P_v);
    // 2. fused qk_in assembly from bf16 P_v (warp + pad)
    k_qkin<<<dim3(73,31,2), bp, 0, stream>>>(P_v, flow_f, flow_b, flows, P_qk);
    // 3. merged big convs: z = {qk img0, qk img1, v img0, v img1}
    k_conv<2,1,0,true,0><<<dim3(15,8,4), 256, 0, stream>>>(
        P_qk, P_v, 992, 960, 31, 30, wT_qk, wT_v, b_qk, b_v,
        nullptr, nullptr, 0, nullptr, Q_tok, V_tok, 0, 0, 2);
    // 4. vproj GEMM + off/attn GEMM + border zeroes (one dispatch)
    k_gemmA<<<2110, 256, 0, stream>>>(
        V_tok, wg_vp, b_vp, vp, Q_tok, wg_oa, b_off, b_at, offs, aw, P_ff, P_mid);
    // 5. deformable sampling (softmax fused, 4-way split) -> acc_tok bf16
    k_sample<<<2560, 256, 0, stream>>>(vp, offs, aw, flows, acc_tok);
    // 6. outproj GEMM -> P_ff interior + srcframe pad -> P_ffn1 (one dispatch)
    k_tailB<<<4860, 256, 0, stream>>>(acc_tok, wg_out, b_out, P_ff,
                                      srcframe, P_ffn1);
    // 7. conv_ff + frame residual -> P_ffn1 cols 0..191 (bf16)
    k_conv<1,1,1,false,1><<<dim3(3,16,10), 256, 0, stream>>>(
        P_ff, nullptr, 192, 0, 6, 0, wT_ff, nullptr, b_ff, nullptr,
        frame, nullptr, 0, nullptr, P_ffn1, nullptr, 384, 0, 1);
    // 8. ffn1 (dilation 2, leaky) -> P_mid
    k_conv<1,2,1,true,0><<<dim3(3,16,10), 256, 0, stream>>>(
        P_ffn1, nullptr, 384, 0, 12, 0, wT_f1, nullptr, b_f1, nullptr,
        nullptr, nullptr, 0, nullptr, P_mid, nullptr, 192, 0, 1);
    // 9. ffn2 + residual(P_ffn1 bf16) -> d_out
    k_conv<1,1,2,false,2><<<dim3(3,16,10), 256, 0, stream>>>(
        P_mid, nullptr, 192, 0, 6, 0, wT_f2, nullptr, b_f2, nullptr,
        nullptr, P_ffn1, 384, out, nullptr, nullptr, 0, 0, 1);
}

// Round 16
// 797.165 us; speedup vs baseline: 1.0174x; 1.0174x over previous
//
#include <hip/hip_runtime.h>

// ---------------------------------------------------------------------------
// DeformableAttnBlock — round 16: round-15 + s_w bank-conflict fix (1056B
// per (tap,cig) group, source-remapped gl_lds; cig groups on banks 0/32/64/96).
// 9 launches. B=2, T=5, C=192, H=W=64, NH=4, NL=5, NP=4, DH=48
// ---------------------------------------------------------------------------

#define HWPX 4096
#define PPXN 4624      // 68*68
#define LQ   20480

typedef __attribute__((ext_vector_type(8))) short  short8;
typedef __attribute__((ext_vector_type(4))) short  short4v;
typedef __attribute__((ext_vector_type(4))) float  f32x4;
typedef __attribute__((ext_vector_type(4))) float  float4v;

__device__ __forceinline__ unsigned short f2bf(float f) {
    unsigned u = __float_as_uint(f);
    unsigned r = (u + 0x7FFF + ((u >> 16) & 1)) >> 16;   // RNE
    return (unsigned short)r;
}
__device__ __forceinline__ float bf2f(unsigned short s) {
    return __uint_as_float(((unsigned)s) << 16);
}

__device__ __forceinline__ void gl_lds16(const unsigned short* g, unsigned short* l) {
    __builtin_amdgcn_global_load_lds(
        (const __attribute__((address_space(1))) unsigned int*)g,
        (__attribute__((address_space(3))) unsigned int*)l, 16, 0, 0);
}

// ---------------------------------------------------------------------------
__device__ __forceinline__ float bsample(const float* __restrict__ p, float sx, float sy) {
    sx = fminf(fmaxf(sx, 0.f), 63.f);
    sy = fminf(fmaxf(sy, 0.f), 63.f);
    float x0 = floorf(sx), y0 = floorf(sy);
    int ix0 = (int)x0, iy0 = (int)y0;
    int ix1 = ix0 < 63 ? ix0 + 1 : 63;
    int iy1 = iy0 < 63 ? iy0 + 1 : 63;
    float wx = sx - x0, wy = sy - y0;
    float v00 = p[iy0*64+ix0], v01 = p[iy0*64+ix1];
    float v10 = p[iy1*64+ix0], v11 = p[iy1*64+ix1];
    return (v00*(1.f-wx) + v01*wx)*(1.f-wy) + (v10*(1.f-wx) + v11*wx)*wy;
}

__device__ void dev_flow(int i, const float* __restrict__ ff,
                         const float* __restrict__ fb, float* __restrict__ flows) {
    int b = i >> 12, pix = i & 4095;
    int x = pix & 63, y = pix >> 6;
    const float* ff01 = ff + (size_t)(b*4+0)*2*HWPX;
    const float* ff12 = ff + (size_t)(b*4+1)*2*HWPX;
    const float* fb32 = fb + (size_t)(b*4+2)*2*HWPX;
    const float* fb43 = fb + (size_t)(b*4+3)*2*HWPX;
    float* F = flows + (size_t)b*5*2*HWPX;
    float ax = ff01[pix], ay = ff01[HWPX+pix];
    float sx = bsample(ff12,      (float)x+ax, (float)y+ay);
    float sy = bsample(ff12+HWPX, (float)x+ax, (float)y+ay);
    F[0*2*HWPX + pix]        = ax + sx;
    F[0*2*HWPX + HWPX + pix] = ay + sy;
    F[1*2*HWPX + pix]        = ff12[pix];
    F[1*2*HWPX + HWPX + pix] = ff12[HWPX+pix];
    F[2*2*HWPX + pix]        = 0.f;
    F[2*2*HWPX + HWPX + pix] = 0.f;
    F[3*2*HWPX + pix]        = fb32[pix];
    F[3*2*HWPX + HWPX + pix] = fb32[HWPX+pix];
    float bx = fb43[pix], by = fb43[HWPX+pix];
    float tx = bsample(fb32,      (float)x+bx, (float)y+by);
    float ty = bsample(fb32+HWPX, (float)x+bx, (float)y+by);
    F[4*2*HWPX + pix]        = bx + tx;
    F[4*2*HWPX + HWPX + pix] = by + ty;
}

__device__ void dev_wT(const float* __restrict__ w, unsigned short* __restrict__ wT,
                       int CI, int NKB, int cotile, int kblk, int tid) {
    unsigned short* dst = wT + ((size_t)(cotile*NKB + kblk))*18432;
    #pragma unroll
    for (int it = 0; it < 9; ++it) {
        int idx = it*256 + tid;
        int tap = idx >> 8, sub = idx & 255;
        int cg = sub >> 6, co = sub & 63;
        int cog = cotile*64 + co;
        int ci0 = kblk*32 + cg*8;
        short8 v;
        #pragma unroll
        for (int j = 0; j < 8; ++j) {
            int ci = ci0 + j;
            v[j] = (ci < CI) ? (short)f2bf(w[((size_t)cog*CI + ci)*9 + tap]) : (short)0;
        }
        *(short8*)(dst + (size_t)idx*8) = v;
    }
}

__device__ void dev_wg(const float* __restrict__ w1, const float* __restrict__ w2,
                       unsigned short* __restrict__ wg, int co_split, int CO,
                       int cotile, int tid) {
    unsigned short* dst = wg + (size_t)cotile*12288;
    #pragma unroll
    for (int it = 0; it < 6; ++it) {
        int idx = it*256 + tid;
        int kblk = idx >> 8, sub = idx & 255;
        int cg = sub >> 6, co = sub & 63;
        int cog = cotile*64 + co;
        int ci0 = kblk*32 + cg*8;
        short8 v = {};
        if (cog < CO) {
            const float* row = (cog < co_split) ? w1 + (size_t)cog*192
                                                : w2 + (size_t)(cog - co_split)*192;
            #pragma unroll
            for (int j = 0; j < 8; ++j) v[j] = (short)f2bf(row[ci0 + j]);
        }
        *(short8*)(dst + (size_t)idx*8) = v;
    }
}

__device__ void dev_pad(const float* __restrict__ in, unsigned short* __restrict__ outb,
                        int CI, int PITCH, int COFF, int img, int ppx_t, int cq, int tid) {
    int ppx = ppx_t*64 + (tid & 63);
    if (ppx >= PPXN) return;
    int c8 = (cq*4 + (tid >> 6))*8;
    unsigned short* dst = outb + ((size_t)img*PPXN + ppx)*PITCH;
    int py = ppx/68, pxc = ppx - py*68;
    if (py < 2 || py >= 66 || pxc < 2 || pxc >= 66) {
        short8 z = {};
        *(short8*)(dst + c8) = z;
        if (COFF) *(short8*)(dst + COFF + c8) = z;
        return;
    }
    int pix = ((py-2)<<6) + (pxc-2);
    short8 o;
    #pragma unroll
    for (int j = 0; j < 8; ++j)
        o[j] = (short)f2bf(in[((size_t)img*CI + c8 + j)*HWPX + pix]);
    *(short8*)(dst + COFF + c8) = o;
}

// ---------------------------------------------------------------------------
// k_wprep: flow + all weight transforms + srcframe->out2 copy + frame pad.
__global__ __launch_bounds__(256) void k_wprep(
    const float* __restrict__ flow_f, const float* __restrict__ flow_b,
    float* __restrict__ flows,
    const float* __restrict__ w_qk, unsigned short* __restrict__ wT_qk,
    const float* __restrict__ w_v,  unsigned short* __restrict__ wT_v,
    const float* __restrict__ w_ff, unsigned short* __restrict__ wT_ff,
    const float* __restrict__ w_f1, unsigned short* __restrict__ wT_f1,
    const float* __restrict__ w_f2, unsigned short* __restrict__ wT_f2,
    const float* __restrict__ w_vp, const float* __restrict__ w_off,
    const float* __restrict__ w_at, const float* __restrict__ w_out,
    unsigned short* __restrict__ wg_vp, unsigned short* __restrict__ wg_oa,
    unsigned short* __restrict__ wg_out,
    const float* __restrict__ srcframe, float* __restrict__ out2,
    const float* __restrict__ frame, unsigned short* __restrict__ P_v)
{
    int bid = blockIdx.x, tid = threadIdx.x;
    if (bid < 32) {
        dev_flow(bid*256 + tid, flow_f, flow_b, flows);
    } else if (bid < 497) {
        int p = bid - 32;   dev_wT(w_qk, wT_qk, 976, 31, p/31, p%31, tid);
    } else if (bid < 947) {
        int p = bid - 497;  dev_wT(w_v,  wT_v,  960, 30, p/30, p%30, tid);
    } else if (bid < 965) {
        int p = bid - 947;  dev_wT(w_ff, wT_ff, 192, 6,  p/6,  p%6,  tid);
    } else if (bid < 1001) {
        int p = bid - 965;  dev_wT(w_f1, wT_f1, 384, 12, p/12, p%12, tid);
    } else if (bid < 1019) {
        int p = bid - 1001; dev_wT(w_f2, wT_f2, 192, 6,  p/6,  p%6,  tid);
    } else if (bid < 1029) {
        int g = bid - 1019;
        if (g < 3)      dev_wg(w_vp,  nullptr, wg_vp, 192, 192, g,   tid);
        else if (g < 7) dev_wg(w_off, w_at,    wg_oa, 160, 240, g-3, tid);
        else            dev_wg(w_out, nullptr, wg_out, 192, 192, g-7, tid);
    } else if (bid < 1989) {
        // srcframe -> out2: 7,864,320 floats = 1,966,080 float4; 8 per thread
        int c = bid - 1029;
        const float4v* s4 = (const float4v*)srcframe;
        float4v* d4 = (float4v*)out2;
        #pragma unroll
        for (int it = 0; it < 8; ++it) {
            int idx = it*245760 + c*256 + tid;
            d4[idx] = s4[idx];
        }
    } else {
        // frame -> P_v padded tok bf16: 4380 = 2 imgs x 30 cq x 73 ppx_t
        int p = bid - 1989;
        int img = p / 2190, rem = p - img*2190;
        int ppx_t = rem % 73, cq = rem / 73;
        dev_pad(frame, P_v, 960, 960, 0, img, ppx_t, cq, tid);
    }
}

// ---------------------------------------------------------------------------
// K2: fused qk_in assembly from bf16 token-major padded P_v.
__global__ void k_qkin(const unsigned short* __restrict__ Pv,
                       const float* __restrict__ ff, const float* __restrict__ fb,
                       const float* __restrict__ flows,
                       unsigned short* __restrict__ Pqk)
{
    int ppx = blockIdx.x*64 + threadIdx.x;
    if (ppx >= PPXN) return;
    int b = blockIdx.z;
    int c8 = (blockIdx.y*4 + threadIdx.y)*8;
    unsigned short* dst = Pqk + ((size_t)b*PPXN + ppx)*992 + c8;
    int py = ppx/68, pxc = ppx - py*68;
    short8 o = {};
    if (py >= 2 && py < 66 && pxc >= 2 && pxc < 66 && c8 < 976) {
        int y = py-2, x = pxc-2, pix = (y<<6)+x;
        if (c8 >= 960) {
            #pragma unroll
            for (int j = 0; j < 8; ++j) {
                int k = c8 - 960 + j;
                float v = (k < 8) ? ff[((size_t)b*8 + k)*HWPX + pix]
                                  : fb[((size_t)b*8 + k - 8)*HWPX + pix];
                o[j] = (short)f2bf(v);
            }
        } else {
            const unsigned short* Pvb = Pv + (size_t)b*PPXN*960;
            int slot = c8/192;
            if (slot == 2) {
                o = *(const short8*)(Pvb + (size_t)ppx*960 + c8);
            } else {
                const float* F = flows + ((size_t)(b*5 + slot)*2)*HWPX;
                float sx = fminf(fmaxf((float)x + F[pix], 0.f), 63.f);
                float sy = fminf(fmaxf((float)y + F[HWPX + pix], 0.f), 63.f);
                float x0 = floorf(sx), y0 = floorf(sy);
                int ix0 = (int)x0, iy0 = (int)y0;
                int ix1 = ix0 < 63 ? ix0+1 : 63, iy1 = iy0 < 63 ? iy0+1 : 63;
                float wx = sx - x0, wy = sy - y0;
                float w00 = (1.f-wx)*(1.f-wy), w01 = wx*(1.f-wy);
                float w10 = (1.f-wx)*wy,       w11 = wx*wy;
                short8 v00 = *(const short8*)(Pvb + ((size_t)((iy0+2)*68 + ix0+2))*960 + c8);
                short8 v01 = *(const short8*)(Pvb + ((size_t)((iy0+2)*68 + ix1+2))*960 + c8);
                short8 v10 = *(const short8*)(Pvb + ((size_t)((iy1+2)*68 + ix0+2))*960 + c8);
                short8 v11 = *(const short8*)(Pvb + ((size_t)((iy1+2)*68 + ix1+2))*960 + c8);
                #pragma unroll
                for (int j = 0; j < 8; ++j) {
                    float v = bf2f((unsigned short)v00[j])*w00 + bf2f((unsigned short)v01[j])*w01
                            + bf2f((unsigned short)v10[j])*w10 + bf2f((unsigned short)v11[j])*w11;
                    o[j] = (short)f2bf(v);
                }
            }
        }
    }
    *(short8*)dst = o;
}

// ---------------------------------------------------------------------------
// k_conv: MFMA implicit-GEMM 3x3 conv. s_w padded: 1056B per (tap,cig) group
// (stride ≡ 32 mod 128 -> 4 cig groups on distinct banks; fixes the 4-way
// A-read conflict). gl_lds dest stays linear; SOURCE remapped (pad = junk).
template<int ROWS, int DIL, int OUTK, bool LEAKY, int RESK>
__global__ __launch_bounds__(256, 2) void k_conv(
    const unsigned short* __restrict__ P0, const unsigned short* __restrict__ P1,
    int CIP0, int CIP1, int NKB0, int NKB1,
    const unsigned short* __restrict__ wT0, const unsigned short* __restrict__ wT1,
    const float* __restrict__ bias0, const float* __restrict__ bias1,
    const float* __restrict__ resF, const unsigned short* __restrict__ resB, int resPitch,
    float* __restrict__ outF,
    unsigned short* __restrict__ outB0, unsigned short* __restrict__ outB1,
    int outPitch, int outCoff, int njobs)
{
    constexpr int RR     = ROWS*4 + 2*DIL;
    constexpr int XP     = 64 + 2*DIL;
    constexpr int PLANE  = RR*XP*16;
    constexpr int NCH    = RR*XP*4;
    constexpr int NXS    = (NCH + 255)/256;
    constexpr int TILEPX = ROWS*4*64;
    constexpr int WGRP   = 66;                // 16B chunks per (tap,cig) group (64+2 pad)
    constexpr int NWCH   = 36*WGRP;           // 2376 chunks = 38,016 B
    constexpr int NWS    = (NWCH + 255)/256;  // 10
    constexpr int SMEM_K = 4*PLANE + NWCH*16;
    constexpr int SMEM_E = (OUTK <= 1) ? TILEPX*72*2 : 0;
    constexpr int SMEMSZ = SMEM_K > SMEM_E ? SMEM_K : SMEM_E;
    __shared__ __align__(16) unsigned char smem[SMEMSZ];
    unsigned char*  s_x = smem;
    unsigned short* s_w = (unsigned short*)(smem + 4*PLANE);

    int tid = threadIdx.x & 255;
    int gx = gridDim.x, gy = gridDim.y, gz = gridDim.z;
    int lin = blockIdx.x + gx*(blockIdx.y + gy*blockIdx.z);
    int tot = gx*gy*gz;
    if ((tot & 7) == 0) { int q = tot >> 3; lin = (lin & 7)*q + (lin >> 3); }
    int cotile = lin % gx; int rem = lin / gx;
    int ytile = rem % gy;  int z = rem / gy;

    int sel = (njobs == 2) ? (z >> 1) : 0;
    int img = (njobs == 2) ? (z & 1)  : z;
    const unsigned short* P  = sel ? P1  : P0;
    const unsigned short* wT = sel ? wT1 : wT0;
    const float* bias        = sel ? bias1 : bias0;
    unsigned short* outB     = sel ? outB1 : outB0;
    int CIP = sel ? CIP1 : CIP0;
    int NKB = sel ? NKB1 : NKB0;

    int y0 = ytile * (ROWS*4);
    const unsigned short* Pi = P + (size_t)img*PPXN*CIP;
    int w = tid >> 6, lane = tid & 63, lm = lane & 15, cig = lane >> 4;

    auto stage_x = [&](int kb) {
        int k0 = kb*32;
        #pragma unroll
        for (int it = 0; it < NXS; ++it) {
            int li = it*256 + tid;
            if (li < NCH) {
                int p = li / (RR*XP), rm = li - p*(RR*XP);
                int r = rm / XP, c = rm - r*XP;
                gl_lds16(Pi + ((size_t)((y0 + 2 - DIL + r)*68 + c + 2 - DIL))*CIP + k0 + p*8,
                         (unsigned short*)(s_x + li*16));
            }
        }
    };
    auto stage_w = [&](int kb) {
        const unsigned short* ws = wT + ((size_t)(cotile*NKB + kb))*18432;
        #pragma unroll
        for (int it = 0; it < NWS; ++it) {
            int li = it*256 + tid;
            if (li < NWCH) {
                int g = li / WGRP, c = li - g*WGRP;
                int sc = (c < 64) ? (g*64 + c) : 0;    // pad chunks load junk
                gl_lds16(ws + (size_t)sc*8, &s_w[li*8]);
            }
        }
    };

    stage_x(0); stage_w(0);
    __syncthreads();

    f32x4 acc[4][ROWS*4] = {};
    for (int kb = 0; kb < NKB; ++kb) {
        __builtin_amdgcn_s_setprio(1);
        #pragma unroll
        for (int t = 0; t < 9; ++t) {
            int ky = t/3, kx = t - ky*3;
            short8 A[4];
            #pragma unroll
            for (int mb = 0; mb < 4; ++mb)
                A[mb] = *(const short8*)&s_w[(t*4 + cig)*(WGRP*8) + (mb*16 + lm)*8];
            #pragma unroll
            for (int s = 0; s < ROWS; ++s) {
                short8 Bf[4];
                #pragma unroll
                for (int nc = 0; nc < 4; ++nc)
                    Bf[nc] = *(const short8*)&s_x[cig*PLANE +
                               ((w*ROWS + s + ky*DIL)*XP + nc*16 + lm + kx*DIL)*16];
                #pragma unroll
                for (int mb = 0; mb < 4; ++mb)
                    #pragma unroll
                    for (int nc = 0; nc < 4; ++nc)
                        acc[mb][s*4+nc] = __builtin_amdgcn_mfma_f32_16x16x32_bf16(
                            A[mb], Bf[nc], acc[mb][s*4+nc], 0, 0, 0);
            }
        }
        __builtin_amdgcn_s_setprio(0);
        __syncthreads();
        if (kb + 1 < NKB) { stage_x(kb+1); stage_w(kb+1); }
        __syncthreads();
    }

    if (OUTK == 0 || OUTK == 1) {
        unsigned short* epi = (unsigned short*)smem;
        #pragma unroll
        for (int mb = 0; mb < 4; ++mb) {
            int cob = cotile*64 + mb*16 + cig*4;
            int col = mb*16 + cig*4;
            #pragma unroll
            for (int s = 0; s < ROWS; ++s) {
                int lr = w*ROWS + s;
                #pragma unroll
                for (int nc = 0; nc < 4; ++nc) {
                    int x = nc*16 + lm;
                    int px_l = lr*64 + x;
                    int gpx = y0*64 + px_l;
                    short4v sv;
                    #pragma unroll
                    for (int r = 0; r < 4; ++r) {
                        float v = acc[mb][s*4+nc][r] + bias[cob + r];
                        if (LEAKY) v = v >= 0.f ? v : 0.1f*v;
                        if (RESK == 1) v += resF[((size_t)img*192 + cob + r)*HWPX + gpx];
                        sv[r] = (short)f2bf(v);
                    }
                    *(short4v*)&epi[px_l*72 + col] = sv;
                }
            }
        }
        __syncthreads();
        constexpr int NCPY = TILEPX/32;
        int slot = (OUTK == 0) ? (cotile*64)/192 : 0;
        int ccb  = (OUTK == 0) ? (cotile*64)%192 : (cotile*64 + outCoff);
        #pragma unroll
        for (int it2 = 0; it2 < NCPY; ++it2) {
            int li = it2*256 + tid;
            int px_l = li >> 3, sub = li & 7;
            short8 v = *(const short8*)&epi[px_l*72 + sub*8];
            int gpx = y0*64 + px_l;
            if (OUTK == 0) {
                *(short8*)(outB + ((size_t)(img*5 + slot)*HWPX + gpx)*192 + ccb + sub*8) = v;
            } else {
                int ppx = ((gpx>>6)+2)*68 + (gpx&63) + 2;
                *(short8*)(outB0 + ((size_t)img*PPXN + ppx)*outPitch + ccb + sub*8) = v;
            }
        }
    } else {
        #pragma unroll
        for (int mb = 0; mb < 4; ++mb) {
            int cob = cotile*64 + mb*16 + cig*4;
            #pragma unroll
            for (int s = 0; s < ROWS; ++s) {
                int y = y0 + w*ROWS + s;
                #pragma unroll
                for (int nc = 0; nc < 4; ++nc) {
                    int x = nc*16 + lm;
                    int px = (y<<6) + x;
                    int ppx = (y+2)*68 + x + 2;
                    short4v rv;
                    if (RESK == 2)
                        rv = *(const short4v*)(resB + ((size_t)img*PPXN + ppx)*resPitch + cob);
                    #pragma unroll
                    for (int r = 0; r < 4; ++r) {
                        float v = acc[mb][s*4+nc][r] + bias[cob + r];
                        if (LEAKY) v = v >= 0.f ? v : 0.1f*v;
                        if (RESK == 1) v += resF[((size_t)img*192 + cob + r)*HWPX + px];
                        if (RESK == 2) v += bf2f((unsigned short)rv[r]);
                        outF[((size_t)img*192 + cob + r)*HWPX + px] = v;
                    }
                }
            }
        }
    }
}

// ---------------------------------------------------------------------------
// GEMM inner core (K=192, 64co x 256px tile); shared arrays declared by caller.
#define GEMM_CORE(Xi, WG_, cotile_)                                              \
    _Pragma("unroll")                                                            \
    for (int it = 0; it < 6; ++it)                                               \
        gl_lds16(WG_ + (size_t)(cotile_)*12288 + (it*256+tid)*8,                 \
                 &s_w[(it*256+tid)*8]);                                          \
    short8 xr[4];                                                                \
    _Pragma("unroll")                                                            \
    for (int it = 0; it < 4; ++it)                                               \
        xr[it] = *(const short8*)(Xi + (size_t)(px0 + tid)*192 + it*8);          \
    _Pragma("unroll")                                                            \
    for (int it = 0; it < 4; ++it)                                               \
        *(short8*)&s_x[0][it*4096 + tid*16] = xr[it];                            \
    __syncthreads();                                                             \
    int w = tid >> 6, lane = tid & 63, lm = lane & 15, cig = lane >> 4;          \
    f32x4 acc[4][4] = {};                                                        \
    int xb = 0;                                                                  \
    for (int kb = 0; kb < 6; ++kb) {                                             \
        bool pf = (kb < 5);                                                      \
        if (pf) {                                                                \
            int k0 = (kb+1)*32;                                                  \
            _Pragma("unroll")                                                    \
            for (int it = 0; it < 4; ++it)                                       \
                xr[it] = *(const short8*)(Xi + (size_t)(px0 + tid)*192 + k0 + it*8); \
        }                                                                        \
        short8 A[4], Bf[4];                                                      \
        _Pragma("unroll")                                                        \
        for (int nb = 0; nb < 4; ++nb)                                           \
            Bf[nb] = *(const short8*)&s_x[xb][cig*4096 + (w*64 + nb*16 + lm)*16];\
        _Pragma("unroll")                                                        \
        for (int mb = 0; mb < 4; ++mb)                                           \
            A[mb] = *(const short8*)&s_w[((kb*4 + cig)*64 + mb*16 + lm)*8];      \
        _Pragma("unroll")                                                        \
        for (int mb = 0; mb < 4; ++mb)                                           \
            _Pragma("unroll")                                                    \
            for (int nb = 0; nb < 4; ++nb)                                       \
                acc[mb][nb] = __builtin_amdgcn_mfma_f32_16x16x32_bf16(           \
                    A[mb], Bf[nb], acc[mb][nb], 0, 0, 0);                        \
        if (pf) {                                                                \
            _Pragma("unroll")                                                    \
            for (int it = 0; it < 4; ++it)                                       \
                *(short8*)&s_x[xb^1][it*4096 + tid*16] = xr[it];                 \
        }                                                                        \
        __syncthreads();                                                         \
        xb ^= 1;                                                                 \
    }

// k_gemmA (flat 2110): [0,480) vproj -> vp h-major [img][4][4096][48];
// [480,1120) off/attn -> offs/aw fp32; [1120,2110) border zeroes P_ff & P_mid.
__global__ __launch_bounds__(256) void k_gemmA(
    const unsigned short* __restrict__ Xv, const unsigned short* __restrict__ WGv,
    const float* __restrict__ bvp, unsigned short* __restrict__ vp,
    const unsigned short* __restrict__ Xq, const unsigned short* __restrict__ WGq,
    const float* __restrict__ boff, const float* __restrict__ batt,
    float* __restrict__ offs, float* __restrict__ aw,
    unsigned short* __restrict__ P_ff, unsigned short* __restrict__ P_mid)
{
    __shared__ unsigned char  s_x[2][4*4096];
    __shared__ unsigned short s_w[12288];
    int tid = threadIdx.x & 255;
    int id = blockIdx.x;
    if (id < 480) {
        int cotile = id % 3, pxt = (id/3) % 16, img = id/48;
        int px0 = pxt*256;
        const unsigned short* Xi = Xv + (size_t)img*HWPX*192;
        GEMM_CORE(Xi, WGv, cotile)
        #pragma unroll
        for (int mb = 0; mb < 4; ++mb) {
            int cob = cotile*64 + mb*16 + cig*4;
            int h = cob/48, d = cob - h*48;
            #pragma unroll
            for (int nb = 0; nb < 4; ++nb) {
                int px = px0 + w*64 + nb*16 + lm;
                short4v s;
                #pragma unroll
                for (int r = 0; r < 4; ++r)
                    s[r] = (short)f2bf(acc[mb][nb][r] + bvp[cob + r]);
                *(short4v*)(vp + (((size_t)img*4 + h)*HWPX + px)*48 + d) = s;
            }
        }
    } else if (id < 1120) {
        int i2 = id - 480;
        int cotile = i2 % 4, pxt = (i2/4) % 16, img = i2/64;
        int px0 = pxt*256;
        const unsigned short* Xi = Xq + (size_t)img*HWPX*192;
        GEMM_CORE(Xi, WGq, cotile)
        int b = img/5, t = img - b*5;
        #pragma unroll
        for (int mb = 0; mb < 4; ++mb) {
            int cob = cotile*64 + mb*16 + cig*4;
            if (cob >= 240) continue;
            #pragma unroll
            for (int nb = 0; nb < 4; ++nb) {
                int px = px0 + w*64 + nb*16 + lm;
                #pragma unroll
                for (int r = 0; r < 4; ++r) {
                    int co = cob + r;
                    float bv = (co < 160) ? boff[co] : batt[co-160];
                    float v = acc[mb][nb][r] + bv;
                    if (co < 160) offs[((size_t)b*160 + co)*LQ + t*HWPX + px] = v;
                    else          aw[((size_t)b*80 + co-160)*LQ + t*HWPX + px] = v;
                }
            }
        }
    } else {
        int u = (id - 1120)*256 + tid;
        int c8i = u % 24; int r1 = u / 24;
        int b = r1 % 528; int r2 = r1 / 528;
        int img = r2 % 10; int buf = r2 / 10;
        int ppx;
        if (b < 136) ppx = b;
        else if (b < 272) ppx = 4488 + (b - 136);
        else { int b2 = b - 272; int row = 2 + (b2 >> 2); int cs = b2 & 3;
               ppx = row*68 + ((cs < 2) ? cs : cs + 64); }
        unsigned short* bp2 = buf ? P_mid : P_ff;
        short8 z = {};
        *(short8*)(bp2 + ((size_t)img*PPXN + ppx)*192 + c8i*8) = z;
    }
}

// k_tailB (flat 4860): [0,480) outproj GEMM -> P_ff interior;
// [480,4860) srcframe pad -> P_ffn1 cols 192..383 + borders.
__global__ __launch_bounds__(256) void k_tailB(
    const unsigned short* __restrict__ X, const unsigned short* __restrict__ WG,
    const float* __restrict__ b1, unsigned short* __restrict__ P_ff,
    const float* __restrict__ srcframe, unsigned short* __restrict__ P_ffn1)
{
    __shared__ unsigned char  s_x[2][4*4096];
    __shared__ unsigned short s_w[12288];
    int tid = threadIdx.x & 255;
    int id = blockIdx.x;
    if (id < 480) {
        int cotile = id % 3, pxt = (id/3) % 16, img = id/48;
        int px0 = pxt*256;
        const unsigned short* Xi = X + (size_t)img*HWPX*192;
        GEMM_CORE(Xi, WG, cotile)
        #pragma unroll
        for (int mb = 0; mb < 4; ++mb) {
            int cob = cotile*64 + mb*16 + cig*4;
            #pragma unroll
            for (int nb = 0; nb < 4; ++nb) {
                int px = px0 + w*64 + nb*16 + lm;
                int ppx = ((px>>6)+2)*68 + (px&63) + 2;
                short4v s;
                #pragma unroll
                for (int r = 0; r < 4; ++r)
                    s[r] = (short)f2bf(acc[mb][nb][r] + b1[cob + r]);
                *(short4v*)(P_ff + ((size_t)img*PPXN + ppx)*192 + cob) = s;
            }
        }
    } else {
        int p = id - 480;
        int img = p / 438, rem = p - img*438;
        int ppx_t = rem % 73, cq = rem / 73;
        dev_pad(srcframe, P_ffn1, 192, 384, 192, img, ppx_t, cq, tid);
    }
}

// ---------------------------------------------------------------------------
// K8: deformable sampling, fused softmax, 4-way split per (lq,h):
// qc = channel-half (24 ch), qt = tap-half (10 taps); combine via shfl_xor(2).
// vp h-major [img][4][4096][48].
__device__ __forceinline__ void addtap24(float* acc, const unsigned short* __restrict__ src, float w) {
    const short8* s8 = (const short8*)src;
    #pragma unroll
    for (int u = 0; u < 3; ++u) {
        short8 v = s8[u];
        #pragma unroll
        for (int j = 0; j < 8; ++j)
            acc[u*8+j] += w * bf2f((unsigned short)v[j]);
    }
}

__global__ __launch_bounds__(256) void k_sample(
    const unsigned short* __restrict__ vp, const float* __restrict__ offs,
    const float* __restrict__ aw, const float* __restrict__ flows,
    unsigned short* __restrict__ accout)
{
    int blk = blockIdx.x;                 // 2560 = 2 b x 1280 sub
    int b = blk / 1280, sub = blk - b*1280;
    int tid = threadIdx.x;
    int lq = sub*16 + (tid >> 4);         // 16 lq per block
    int h  = (tid >> 2) & 3;              // 4 heads
    int qt = (tid >> 1) & 1;              // tap half
    int qc = tid & 1;                     // channel half
    int pix = lq & 4095;
    int x = pix & 63, y = pix >> 6;
    const float* offp = offs + ((size_t)b*160 + h*40)*LQ + lq;
    const float* awp  = aw   + ((size_t)b*80  + h*20)*LQ + lq;
    float e[20];
    float m = -1e30f;
    #pragma unroll
    for (int j = 0; j < 20; ++j) { e[j] = awp[(size_t)j*LQ]; m = fmaxf(m, e[j]); }
    float ssum = 0.f;
    #pragma unroll
    for (int j = 0; j < 20; ++j) { e[j] = __expf(e[j]-m); ssum += e[j]; }
    float inv = 1.f/ssum;

    float acc[24];
    #pragma unroll
    for (int d = 0; d < 24; ++d) acc[d] = 0.f;

    int o0 = qt*10;
    #pragma unroll
    for (int oi = 0; oi < 10; ++oi) {
        int o = o0 + oi;
        int l = o >> 2;
        float fx = flows[((size_t)(b*5+l)*2+0)*HWPX + pix];
        float fy = flows[((size_t)(b*5+l)*2+1)*HWPX + pix];
        const unsigned short* vpl = vp + (((size_t)(b*5+l)*4 + h)*HWPX)*48 + qc*24;
        float ox = offp[(size_t)(2*o)*LQ];
        float oy = offp[(size_t)(2*o+1)*LQ];
        float wv = e[o]*inv;
        float sx = (float)x + ox + fx;
        float sy = (float)y + oy + fy;
        float x0f = floorf(sx), y0f = floorf(sy);
        float wx = sx - x0f, wy = sy - y0f;
        int ix0 = (int)x0f, iy0 = (int)y0f;
        float w00 = wv*(1.f-wx)*(1.f-wy), w01 = wv*wx*(1.f-wy);
        float w10 = wv*(1.f-wx)*wy,       w11 = wv*wx*wy;
        bool vx0 = (ix0 >= 0)  && (ix0 <= 63);
        bool vx1 = (ix0 >= -1) && (ix0 <= 62);
        bool vy0 = (iy0 >= 0)  && (iy0 <= 63);
        bool vy1 = (iy0 >= -1) && (iy0 <= 62);
        if (vy0 && vx0) addtap24(acc, vpl + (size_t)(iy0*64 + ix0)*48,       w00);
        if (vy0 && vx1) addtap24(acc, vpl + (size_t)(iy0*64 + ix0 + 1)*48,   w01);
        if (vy1 && vx0) addtap24(acc, vpl + (size_t)((iy0+1)*64 + ix0)*48,   w10);
        if (vy1 && vx1) addtap24(acc, vpl + (size_t)((iy0+1)*64 + ix0+1)*48, w11);
    }
    // combine tap halves (lanes tid and tid^2 are in the same wave)
    #pragma unroll
    for (int d = 0; d < 24; ++d)
        acc[d] += __shfl_xor(acc[d], 2);
    if (qt == 0) {
        unsigned short* dst = accout + ((size_t)b*LQ + lq)*192 + h*48 + qc*24;
        #pragma unroll
        for (int u = 0; u < 3; ++u) {
            short8 s;
            #pragma unroll
            for (int j = 0; j < 8; ++j) s[j] = (short)f2bf(acc[u*8+j]);
            *(short8*)(dst + u*8) = s;
        }
    }
}

// ---------------------------------------------------------------------------

extern "C" void kernel_launch(void* const* d_in, const int* in_sizes, int n_in,
                              void* d_out, int out_size, void* d_ws, size_t ws_size,
                              hipStream_t stream) {
    (void)in_sizes; (void)n_in; (void)out_size; (void)ws_size;
    const float* frame    = (const float*)d_in[0];
    const float* srcframe = (const float*)d_in[1];
    const float* flow_f   = (const float*)d_in[2];
    const float* flow_b   = (const float*)d_in[3];
    const float* w_qk  = (const float*)d_in[4];  const float* b_qk  = (const float*)d_in[5];
    const float* w_v   = (const float*)d_in[6];  const float* b_v   = (const float*)d_in[7];
    const float* w_vp  = (const float*)d_in[8];  const float* b_vp  = (const float*)d_in[9];
    const float* w_off = (const float*)d_in[10]; const float* b_off = (const float*)d_in[11];
    const float* w_at  = (const float*)d_in[12]; const float* b_at  = (const float*)d_in[13];
    const float* w_out = (const float*)d_in[14]; const float* b_out = (const float*)d_in[15];
    const float* w_ff  = (const float*)d_in[16]; const float* b_ff  = (const float*)d_in[17];
    const float* w_f1  = (const float*)d_in[18]; const float* b_f1  = (const float*)d_in[19];
    const float* w_f2  = (const float*)d_in[20]; const float* b_f2  = (const float*)d_in[21];
    float* out = (float*)d_out;
    char* W = (char*)d_ws;

    // ---- workspace layout (bytes), all regions disjoint; max 163,624,960 ----
    float*          flows  = (float*)(W + 0);                    // 327,680
    unsigned short* wT_qk  = (unsigned short*)(W + 327680);      // 17,141,760
    unsigned short* wT_v   = (unsigned short*)(W + 17469440);    // 16,588,800 -> 34,058,240
    unsigned short* P_qk   = (unsigned short*)(W + 34058240);    // 18,348,032
    unsigned short* P_ff   = P_qk;                               // reuse
    unsigned short* P_v    = (unsigned short*)(W + 52406272);    // 17,756,160
    unsigned short* P_mid  = P_v;                                // reuse
    unsigned short* Q_tok  = (unsigned short*)(W + 70162432);    // 15,728,640
    unsigned short* acc_tok= Q_tok;                              // reuse
    unsigned short* V_tok  = (unsigned short*)(W + 85891072);    // 15,728,640
    unsigned short* P_ffn1 = V_tok;                              // reuse (extends into vp after vp dead)
    unsigned short* vp     = (unsigned short*)(W + 101619712);   // 15,728,640
    float*          offs   = (float*)(W + 121403392);            // 26,214,400
    float*          aw     = (float*)(W + 147617792);            // 13,107,200 -> 160,724,992
    unsigned short* wT_ff  = (unsigned short*)(W + 160724992);   //   663,552
    unsigned short* wT_f1  = (unsigned short*)(W + 161388544);   // 1,327,104
    unsigned short* wT_f2  = (unsigned short*)(W + 162715648);   //   663,552
    unsigned short* wg_vp  = (unsigned short*)(W + 163379200);   //    73,728
    unsigned short* wg_oa  = (unsigned short*)(W + 163452928);   //    98,304
    unsigned short* wg_out = (unsigned short*)(W + 163551232);   //    73,728 -> 163,624,960

    dim3 bp(64, 4);

    // 1. flow + weight transforms + srcframe copy + frame pad (one dispatch)
    k_wprep<<<6369, 256, 0, stream>>>(
        flow_f, flow_b, flows,
        w_qk, wT_qk, w_v, wT_v, w_ff, wT_ff, w_f1, wT_f1, w_f2, wT_f2,
        w_vp, w_off, w_at, w_out, wg_vp, wg_oa, wg_out,
        srcframe, out + (size_t)2*5*192*HWPX, frame, P_v);
    // 2. fused qk_in assembly from bf16 P_v (warp + pad)
    k_qkin<<<dim3(73,31,2), bp, 0, stream>>>(P_v, flow_f, flow_b, flows, P_qk);
    // 3. merged big convs: z = {qk img0, qk img1, v img0, v img1}
    k_conv<2,1,0,true,0><<<dim3(15,8,4), 256, 0, stream>>>(
        P_qk, P_v, 992, 960, 31, 30, wT_qk, wT_v, b_qk, b_v,
        nullptr, nullptr, 0, nullptr, Q_tok, V_tok, 0, 0, 2);
    // 4. vproj GEMM + off/attn GEMM + border zeroes (one dispatch)
    k_gemmA<<<2110, 256, 0, stream>>>(
        V_tok, wg_vp, b_vp, vp, Q_tok, wg_oa, b_off, b_at, offs, aw, P_ff, P_mid);
    // 5. deformable sampling (softmax fused, 4-way split) -> acc_tok bf16
    k_sample<<<2560, 256, 0, stream>>>(vp, offs, aw, flows, acc_tok);
    // 6. outproj GEMM -> P_ff interior + srcframe pad -> P_ffn1 (one dispatch)
    k_tailB<<<4860, 256, 0, stream>>>(acc_tok, wg_out, b_out, P_ff,
                                      srcframe, P_ffn1);
    // 7. conv_ff + frame residual -> P_ffn1 cols 0..191 (bf16)
    k_conv<1,1,1,false,1><<<dim3(3,16,10), 256, 0, stream>>>(
        P_ff, nullptr, 192, 0, 6, 0, wT_ff, nullptr, b_ff, nullptr,
        frame, nullptr, 0, nullptr, P_ffn1, nullptr, 384, 0, 1);
    // 8. ffn1 (dilation 2, leaky) -> P_mid
    k_conv<1,2,1,true,0><<<dim3(3,16,10), 256, 0, stream>>>(
        P_ffn1, nullptr, 384, 0, 12, 0, wT_f1, nullptr, b_f1, nullptr,
        nullptr, nullptr, 0, nullptr, P_mid, nullptr, 192, 0, 1);
    // 9. ffn2 + residual(P_ffn1 bf16) -> d_out
    k_conv<1,1,2,false,2><<<dim3(3,16,10), 256, 0, stream>>>(
        P_mid, nullptr, 192, 0, 6, 0, wT_f2, nullptr, b_f2, nullptr,
        nullptr, P_ffn1, 384, out, nullptr, nullptr, 0, 0, 1);
}